// Round 13
// baseline (124.873 us; speedup 1.0000x reference)
//
#include <hip/hip_runtime.h>
#include <hip/hip_bf16.h>
#include <cstddef>
#include <cstdint>

#define BATCH 131072
#define HOFF ((size_t)BATCH * 66)

typedef __attribute__((ext_vector_type(8))) short short8;
typedef __attribute__((ext_vector_type(4))) short short4v;
typedef __attribute__((ext_vector_type(4))) float f32x4;
typedef __attribute__((ext_vector_type(16))) float f32x16;

typedef const __attribute__((address_space(1))) unsigned int* gas_t;
typedef __attribute__((address_space(3))) unsigned int* las_t;

// d_ws (bf16 elems):
//  [0,6656): F0 fuse rows 0..63 [64][104]   [6656,13312): F1 fuse rows 64..127
//  [13312 + (u*3+p)*8704): GRU unit u pair p = [2][32][136]
//     p0: {ir, hr}   p1: {hn, in}   p2: {iz, hz}
//  [117760 + h*8704): head pair h: h0/h1 ns1, h2 ns2, h3 rw1, h4 dn1
#define WS_G      13312
#define WS_HEAD   117760
#define WS_ELEMS  161280

// smem (shorts): slot A [0,8704) | slot B [8704,17408) | strips 4 x 1280 [17408,22528)
#define SLOT_A    0
#define SLOT_B    8704
#define STR_BASE  17408

#define MFMA32(a,b,c) __builtin_amdgcn_mfma_f32_32x32x16_bf16((a),(b),(c),0,0,0)

__device__ __forceinline__ short f2bf(float x) {
    __hip_bfloat16 b = __float2bfloat16(x);
    return __builtin_bit_cast(short, b);
}
__device__ __forceinline__ float bf2f(short s) {
    unsigned u = ((unsigned)(unsigned short)s) << 16;
    return __builtin_bit_cast(float, u);
}
__device__ __forceinline__ float fsigmoid(float x) { return __builtin_amdgcn_rcpf(1.0f + __expf(-x)); }
__device__ __forceinline__ float ftanh(float x)    { return 1.0f - 2.0f * __builtin_amdgcn_rcpf(1.0f + __expf(2.0f * x)); }

__device__ __forceinline__ short8 packbf(f32x4 a, f32x4 b) {
    short8 r;
    r[0]=f2bf(a[0]); r[1]=f2bf(a[1]); r[2]=f2bf(a[2]); r[3]=f2bf(a[3]);
    r[4]=f2bf(b[0]); r[5]=f2bf(b[1]); r[6]=f2bf(b[2]); r[7]=f2bf(b[3]);
    return r;
}

// async global->LDS, 256-thread chunking; tail guards wave-uniform
template<int NCH>
__device__ __forceinline__ void stage_lds(const short* __restrict__ src, short* dst, int t) {
    constexpr int NP = (NCH + 255) / 256;
    #pragma unroll
    for (int k = 0; k < NP; ++k) {
        int c = t + 256 * k;
        if ((NCH % 256 == 0) || c < NCH)
            __builtin_amdgcn_global_load_lds((gas_t)(const void*)(src + (size_t)c * 8),
                                             (las_t)(void*)(dst + (size_t)c * 8), 16, 0, 0);
    }
}

// ---------------- prep: f32 weights -> bf16 pair-slots in d_ws (unchanged) ----------------
extern "C" __global__ void prep_weights(const float* __restrict__ fuse_W,
                                        const float* __restrict__ W_ih, const float* __restrict__ W_hh,
                                        const float* __restrict__ ns_W1, const float* __restrict__ ns_W2,
                                        const float* __restrict__ rw_W1, const float* __restrict__ dn_W1,
                                        short* __restrict__ ws) {
    int i = blockIdx.x * 256 + threadIdx.x;
    if (i >= WS_ELEMS) return;
    float v = 0.f;
    if (i < WS_G) {                          // fuse halves [64][104], K padded 80->104
        int half = i / 6656, e = i % 6656;
        int r = e / 104, k = e % 104;
        if (k < 80) v = fuse_W[(size_t)(half*64 + r)*80 + k];
    } else if (i < WS_HEAD) {                // GRU pairs
        int rel = i - WS_G;
        int pidx = rel / 8704, e = rel % 8704;
        int q = e / 4352, r = (e % 4352) / 136, k = e % 136;
        if (k < 128) {
            int u = pidx / 3, p = pidx % 3;
            const float* W; int gate;
            if (p == 0)      { W = q ? W_hh : W_ih; gate = 0; }   // {ir, hr}
            else if (p == 1) { W = q ? W_ih : W_hh; gate = 2; }   // {hn, in}
            else             { W = q ? W_hh : W_ih; gate = 1; }   // {iz, hz}
            v = W[(size_t)(gate*128 + u*32 + r)*128 + k];
        }
    } else {                                 // head pairs
        int rel = i - WS_HEAD;
        int h = rel / 8704, e = rel % 8704;
        int q = e / 4352, r = (e % 4352) / 136, k = e % 136;
        if (k < 128) {
            const float* W; int rb;
            if (h == 0)      { W = ns_W1; rb = q*32; }
            else if (h == 1) { W = ns_W1; rb = 64 + q*32; }
            else if (h == 2) { W = ns_W2; rb = q*32; }
            else if (h == 3) { W = rw_W1; rb = q*32; }
            else             { W = dn_W1; rb = q*32; }
            v = W[(size_t)(rb + r)*128 + k];
        }
    }
    ws[i] = f2bf(v);
}

// GRU r-phase: h0 slice direct from global (D-layout, coalesced 128B rows); rg -> tmp
#define GRU_R(SB, U) do {                                                                  \
    const int cb = (U)*32 + ln;                                                            \
    _Pragma("unroll") for (int p = 0; p < 8; ++p) {                                        \
        const int r0 = ((2*p)&3) + 8*(p>>1) + hr4;                                         \
        unsigned a = (unsigned short)f2bf(hidden[(size_t)(R + r0    )*128 + cb]);          \
        unsigned b = (unsigned short)f2bf(hidden[(size_t)(R + r0 + 1)*128 + cb]);          \
        h0p[p] = a | (b << 16);                                                            \
    }                                                                                      \
    const float br = b_ih[cb] + b_hh[cb];                                                  \
    f32x16 acc = zz16;                                                                     \
    _Pragma("unroll") for (int kf = 0; kf < 8; ++kf) {                                     \
        const int ko = kf*16 + hb8;                                                        \
        short8 B0 = *(const short8*)&smem[(SB) + ln*136 + ko];                             \
        acc = MFMA32(xa[kf], B0, acc);                                                     \
        short8 B1 = *(const short8*)&smem[(SB) + (32 + ln)*136 + ko];                      \
        acc = MFMA32(ha[kf], B1, acc);                                                     \
    }                                                                                      \
    _Pragma("unroll") for (int reg = 0; reg < 16; ++reg)                                   \
        tmp[reg] = fsigmoid(acc[reg] + br);                                                \
} while (0)

// GRU n-phase: tmp = tanh(ain + bin + rg*(ahn + bhn))
#define GRU_N(SB, U) do {                                                                  \
    const int cb = (U)*32 + ln;                                                            \
    const float bin = b_ih[256 + cb], bhn = b_hh[256 + cb];                                \
    f32x16 acc = zz16;                                                                     \
    _Pragma("unroll") for (int kf = 0; kf < 8; ++kf) {                                     \
        short8 B = *(const short8*)&smem[(SB) + ln*136 + kf*16 + hb8];                     \
        acc = MFMA32(ha[kf], B, acc);                                                      \
    }                                                                                      \
    _Pragma("unroll") for (int reg = 0; reg < 16; ++reg)                                   \
        tmp[reg] = tmp[reg] * (acc[reg] + bhn);                                            \
    acc = zz16;                                                                            \
    _Pragma("unroll") for (int kf = 0; kf < 8; ++kf) {                                     \
        short8 B = *(const short8*)&smem[(SB) + (32 + ln)*136 + kf*16 + hb8];              \
        acc = MFMA32(xa[kf], B, acc);                                                      \
    }                                                                                      \
    _Pragma("unroll") for (int reg = 0; reg < 16; ++reg)                                   \
        tmp[reg] = ftanh(acc[reg] + bin + tmp[reg]);                                       \
} while (0)

// GRU z-phase: h_new stored DIRECTLY to out (f32 exact, coalesced 128B segments)
#define GRU_Z(SB, U) do {                                                                  \
    const int cb = (U)*32 + ln;                                                            \
    const float bz = b_ih[128 + cb] + b_hh[128 + cb];                                      \
    f32x16 acc = zz16;                                                                     \
    _Pragma("unroll") for (int kf = 0; kf < 8; ++kf) {                                     \
        const int ko = kf*16 + hb8;                                                        \
        short8 B0 = *(const short8*)&smem[(SB) + ln*136 + ko];                             \
        acc = MFMA32(xa[kf], B0, acc);                                                     \
        short8 B1 = *(const short8*)&smem[(SB) + (32 + ln)*136 + ko];                      \
        acc = MFMA32(ha[kf], B1, acc);                                                     \
    }                                                                                      \
    _Pragma("unroll") for (int p = 0; p < 8; ++p) {                                        \
        unsigned hp = h0p[p];                                                              \
        const int r0 = ((2*p)&3) + 8*(p>>1) + hr4;                                         \
        {   float h0v = bf2f((short)(hp & 0xffffu));                                       \
            float zg = fsigmoid(acc[2*p] + bz);                                            \
            out[HOFF + (size_t)(R + r0)*128 + cb] = (1.f - zg)*tmp[2*p] + zg*h0v; }        \
        {   float h0v = bf2f((short)(hp >> 16));                                           \
            float zg = fsigmoid(acc[2*p+1] + bz);                                          \
            out[HOFF + (size_t)(R + r0 + 1)*128 + cb] = (1.f - zg)*tmp[2*p+1] + zg*h0v; }  \
    }                                                                                      \
} while (0)

// head GEMM -> strip (for A-frag recapture / hpartial)
#define HEAD32(FRAG, BIASEXPR, SB, Q, RELU) do {                                           \
    f32x16 a = zz16;                                                                       \
    _Pragma("unroll") for (int kf = 0; kf < 8; ++kf) {                                     \
        short8 B = *(const short8*)&smem[(SB) + (Q)*4352 + ln*136 + kf*16 + hb8];          \
        a = MFMA32((FRAG)[kf], B, a);                                                      \
    }                                                                                      \
    const float bb = (BIASEXPR);                                                           \
    _Pragma("unroll") for (int reg = 0; reg < 16; ++reg) {                                 \
        float v = a[reg] + bb;                                                             \
        if (RELU) v = fmaxf(v, 0.f);                                                       \
        S[((reg&3) + 8*(reg>>2) + hr4)*40 + ln] = f2bf(v);                                 \
    }                                                                                      \
} while (0)

// head GEMM -> direct global store (z_next, f32 exact)
#define HEAD32_ST(FRAG, BIASEXPR, SB, Q, QCOL) do {                                        \
    f32x16 a = zz16;                                                                       \
    _Pragma("unroll") for (int kf = 0; kf < 8; ++kf) {                                     \
        short8 B = *(const short8*)&smem[(SB) + (Q)*4352 + ln*136 + kf*16 + hb8];          \
        a = MFMA32((FRAG)[kf], B, a);                                                      \
    }                                                                                      \
    const float bb = (BIASEXPR);                                                           \
    _Pragma("unroll") for (int reg = 0; reg < 16; ++reg) {                                 \
        const int row = (reg&3) + 8*(reg>>2) + hr4;                                        \
        out[(size_t)(R + row)*64 + (QCOL)*32 + ln] = a[reg] + bb;                          \
    }                                                                                      \
} while (0)

// ---------------- main fused kernel: 256 threads (4 waves x 32 rows), grid 1024 ----------------
extern "C" __global__ __launch_bounds__(256, 1)
void gru_mfma(const float* __restrict__ z_t, const int* __restrict__ action,
              const float* __restrict__ hidden, const float* __restrict__ embed,
              const float* __restrict__ fuse_b,
              const float* __restrict__ b_ih, const float* __restrict__ b_hh,
              const float* __restrict__ ns_b1, const float* __restrict__ ns_b2,
              const float* __restrict__ rw_b1, const float* __restrict__ rw_W2, const float* __restrict__ rw_b2,
              const float* __restrict__ dn_b1, const float* __restrict__ dn_W2, const float* __restrict__ dn_b2,
              const short* __restrict__ ws, float* out)
{
    __shared__ __align__(16) short smem[22528];   // 45.1 KB

    const int t    = threadIdx.x;
    const int lane = t & 63;
    const int w    = t >> 6;
    const int ln   = lane & 31;
    const int hb8  = (lane >> 5) * 8;
    const int hr4  = (lane >> 5) * 4;
    const int R    = blockIdx.x * 128 + w * 32;
    short* const S = &smem[STR_BASE + w * 1280];  // per-wave strip [32][40] (fuse/heads only)

    const f32x16 zz16 = {0,0,0,0,0,0,0,0,0,0,0,0,0,0,0,0};

    auto hpartial = [&](const float* W2, float acc) -> float {
        int rr = lane & 31;
        #pragma unroll
        for (int kk = 0; kk < 32; kk += 8) {
            short8 s = *(const short8*)&S[rr*40 + kk];
            f32x4 w0 = *(const f32x4*)&W2[kk];
            f32x4 w1 = *(const f32x4*)&W2[kk+4];
            acc += bf2f(s[0])*w0[0] + bf2f(s[1])*w0[1] + bf2f(s[2])*w0[2] + bf2f(s[3])*w0[3]
                 + bf2f(s[4])*w1[0] + bf2f(s[5])*w1[1] + bf2f(s[6])*w1[2] + bf2f(s[7])*w1[3];
        }
        return acc;
    };

    // ---- pre-loop: stage F0 -> A; A-fragment global loads ----
    stage_lds<832>(ws, &smem[SLOT_A], t);

    short8 fa[5];
    short8 ha[8];
    {
        const int row = R + ln;
        #pragma unroll
        for (int kf = 0; kf < 4; ++kf) {
            f32x4 p0 = *(const f32x4*)&z_t[(size_t)row*64 + kf*16 + hb8];
            f32x4 p1 = *(const f32x4*)&z_t[(size_t)row*64 + kf*16 + hb8 + 4];
            fa[kf] = packbf(p0, p1);
        }
        int a = action[row];
        f32x4 e0 = *(const f32x4*)&embed[a*16 + hb8];
        f32x4 e1 = *(const f32x4*)&embed[a*16 + hb8 + 4];
        fa[4] = packbf(e0, e1);
        #pragma unroll
        for (int kf = 0; kf < 8; ++kf) {
            f32x4 p0 = *(const f32x4*)&hidden[(size_t)row*128 + kf*16 + hb8];
            f32x4 p1 = *(const f32x4*)&hidden[(size_t)row*128 + kf*16 + hb8 + 4];
            ha[kf] = packbf(p0, p1);
        }
    }

    short8 xa[8];
    f32x16 tmp;
    unsigned h0p[8];

    __syncthreads();                                   // B0: F0 resident
    stage_lds<832>(ws + 6656, &smem[SLOT_B], t);       // F1 for P1
    // P0: fuse cols 0..63 from A
    #pragma unroll
    for (int n = 0; n < 2; ++n) {
        f32x16 a = zz16;
        #pragma unroll
        for (int kf = 0; kf < 5; ++kf) {
            short8 B = *(const short8*)&smem[SLOT_A + (n*32 + ln)*104 + kf*16 + hb8];
            a = MFMA32(fa[kf], B, a);
        }
        float fb = fuse_b[n*32 + ln];
        #pragma unroll
        for (int reg = 0; reg < 16; ++reg)
            S[((reg&3) + 8*(reg>>2) + hr4)*40 + ln] = f2bf(fmaxf(a[reg] + fb, 0.f));
        xa[2*n]   = *(const short8*)&S[ln*40 + hb8];
        xa[2*n+1] = *(const short8*)&S[ln*40 + 16 + hb8];
    }

    __syncthreads();                                   // B1
    stage_lds<1088>(ws + WS_G + 0*8704, &smem[SLOT_A], t);
    // P1: fuse cols 64..127 from B
    #pragma unroll
    for (int n = 2; n < 4; ++n) {
        f32x16 a = zz16;
        #pragma unroll
        for (int kf = 0; kf < 5; ++kf) {
            short8 B = *(const short8*)&smem[SLOT_B + ((n-2)*32 + ln)*104 + kf*16 + hb8];
            a = MFMA32(fa[kf], B, a);
        }
        float fb = fuse_b[n*32 + ln];
        #pragma unroll
        for (int reg = 0; reg < 16; ++reg)
            S[((reg&3) + 8*(reg>>2) + hr4)*40 + ln] = f2bf(fmaxf(a[reg] + fb, 0.f));
        xa[2*n]   = *(const short8*)&S[ln*40 + hb8];
        xa[2*n+1] = *(const short8*)&S[ln*40 + 16 + hb8];
    }

    // ---- GRU: u = 0..3, phases r/n/z, slots alternate ----
    __syncthreads();                                   // B2
    stage_lds<1088>(ws + WS_G + 1*8704, &smem[SLOT_B], t);
    GRU_R(SLOT_A, 0);                                  // P2
    __syncthreads();                                   // B3
    stage_lds<1088>(ws + WS_G + 2*8704, &smem[SLOT_A], t);
    GRU_N(SLOT_B, 0);                                  // P3
    __syncthreads();                                   // B4
    stage_lds<1088>(ws + WS_G + 3*8704, &smem[SLOT_B], t);
    GRU_Z(SLOT_A, 0);                                  // P4
    __syncthreads();                                   // B5
    stage_lds<1088>(ws + WS_G + 4*8704, &smem[SLOT_A], t);
    GRU_R(SLOT_B, 1);                                  // P5
    __syncthreads();                                   // B6
    stage_lds<1088>(ws + WS_G + 5*8704, &smem[SLOT_B], t);
    GRU_N(SLOT_A, 1);                                  // P6
    __syncthreads();                                   // B7
    stage_lds<1088>(ws + WS_G + 6*8704, &smem[SLOT_A], t);
    GRU_Z(SLOT_B, 1);                                  // P7
    __syncthreads();                                   // B8
    stage_lds<1088>(ws + WS_G + 7*8704, &smem[SLOT_B], t);
    GRU_R(SLOT_A, 2);                                  // P8
    __syncthreads();                                   // B9
    stage_lds<1088>(ws + WS_G + 8*8704, &smem[SLOT_A], t);
    GRU_N(SLOT_B, 2);                                  // P9
    __syncthreads();                                   // B10
    stage_lds<1088>(ws + WS_G + 9*8704, &smem[SLOT_B], t);
    GRU_Z(SLOT_A, 2);                                  // P10
    __syncthreads();                                   // B11
    stage_lds<1088>(ws + WS_G + 10*8704, &smem[SLOT_A], t);
    GRU_R(SLOT_B, 3);                                  // P11
    __syncthreads();                                   // B12
    stage_lds<1088>(ws + WS_G + 11*8704, &smem[SLOT_B], t);
    GRU_N(SLOT_A, 3);                                  // P12
    __syncthreads();                                   // B13
    stage_lds<1088>(ws + WS_HEAD + 0*8704, &smem[SLOT_A], t);
    GRU_Z(SLOT_B, 3);                                  // P13

    // ---- heads (parity: h0->A, h1->B, h2->A, h3->B, h4->A) ----
    __syncthreads();                                   // B14 (drains h_new stores)
    stage_lds<1088>(ws + WS_HEAD + 1*8704, &smem[SLOT_B], t);
    // reload h_new A-frags from out (L2-hot, coalesced)
    short8 hfa[8];
    #pragma unroll
    for (int kf = 0; kf < 8; ++kf) {
        const float* p = &out[HOFF + (size_t)(R + ln)*128 + kf*16 + hb8];
        f32x4 p0 = *(const f32x4*)p;
        f32x4 p1 = *(const f32x4*)(p + 4);
        hfa[kf] = packbf(p0, p1);
    }
    short8 ta[8];
    HEAD32(hfa, ns_b1[ln],      SLOT_A, 0, true);      // P14: ns1 q0,q1 (h0 in A)
    ta[0] = *(const short8*)&S[ln*40 + hb8];
    ta[1] = *(const short8*)&S[ln*40 + 16 + hb8];
    HEAD32(hfa, ns_b1[32 + ln], SLOT_A, 1, true);
    ta[2] = *(const short8*)&S[ln*40 + hb8];
    ta[3] = *(const short8*)&S[ln*40 + 16 + hb8];

    __syncthreads();                                   // B15
    stage_lds<1088>(ws + WS_HEAD + 2*8704, &smem[SLOT_A], t);
    HEAD32(hfa, ns_b1[64 + ln], SLOT_B, 0, true);      // P15: ns1 q2,q3 (h1 in B)
    ta[4] = *(const short8*)&S[ln*40 + hb8];
    ta[5] = *(const short8*)&S[ln*40 + 16 + hb8];
    HEAD32(hfa, ns_b1[96 + ln], SLOT_B, 1, true);
    ta[6] = *(const short8*)&S[ln*40 + hb8];
    ta[7] = *(const short8*)&S[ln*40 + 16 + hb8];

    __syncthreads();                                   // B16
    stage_lds<1088>(ws + WS_HEAD + 3*8704, &smem[SLOT_B], t);
    HEAD32_ST(ta, ns_b2[ln],      SLOT_A, 0, 0);       // P16: ns2 (h2 in A) -> z_next direct
    HEAD32_ST(ta, ns_b2[32 + ln], SLOT_A, 1, 1);

    __syncthreads();                                   // B17
    stage_lds<1088>(ws + WS_HEAD + 4*8704, &smem[SLOT_A], t);
    float racc = rw_b2[0];                             // P17: rw1 (h3 in B) + reward dot
    HEAD32(hfa, rw_b1[ln],      SLOT_B, 0, true);
    racc = hpartial(rw_W2, racc);
    HEAD32(hfa, rw_b1[32 + ln], SLOT_B, 1, true);
    racc = hpartial(rw_W2 + 32, racc);
    if (lane < 32) out[(size_t)BATCH*64 + R + ln] = racc;

    __syncthreads();                                   // B18
    float dacc = dn_b2[0];                             // P18: dn1 (h4 in A) + done dot
    HEAD32(hfa, dn_b1[ln],      SLOT_A, 0, true);
    dacc = hpartial(dn_W2, dacc);
    HEAD32(hfa, dn_b1[32 + ln], SLOT_A, 1, true);
    dacc = hpartial(dn_W2 + 32, dacc);
    if (lane < 32) out[(size_t)BATCH*65 + R + ln] = dacc;
}

extern "C" void kernel_launch(void* const* d_in, const int* in_sizes, int n_in,
                              void* d_out, int out_size, void* d_ws, size_t ws_size,
                              hipStream_t stream) {
    const float* z_t    = (const float*)d_in[0];
    const int*   action = (const int*)  d_in[1];
    const float* hidden = (const float*)d_in[2];
    const float* embed  = (const float*)d_in[3];
    const float* fuse_W = (const float*)d_in[4];
    const float* fuse_b = (const float*)d_in[5];
    const float* W_ih   = (const float*)d_in[6];
    const float* W_hh   = (const float*)d_in[7];
    const float* b_ih   = (const float*)d_in[8];
    const float* b_hh   = (const float*)d_in[9];
    const float* ns_W1  = (const float*)d_in[10];
    const float* ns_b1  = (const float*)d_in[11];
    const float* ns_W2  = (const float*)d_in[12];
    const float* ns_b2  = (const float*)d_in[13];
    const float* rw_W1  = (const float*)d_in[14];
    const float* rw_b1  = (const float*)d_in[15];
    const float* rw_W2  = (const float*)d_in[16];
    const float* rw_b2  = (const float*)d_in[17];
    const float* dn_W1  = (const float*)d_in[18];
    const float* dn_b1  = (const float*)d_in[19];
    const float* dn_W2  = (const float*)d_in[20];
    const float* dn_b2  = (const float*)d_in[21];
    float* out = (float*)d_out;
    short* ws  = (short*)d_ws;

    hipLaunchKernelGGL(prep_weights, dim3((WS_ELEMS + 255) / 256), dim3(256), 0, stream,
                       fuse_W, W_ih, W_hh, ns_W1, ns_W2, rw_W1, dn_W1, ws);

    hipLaunchKernelGGL(gru_mfma, dim3(BATCH / 128), dim3(256), 0, stream,
                       z_t, action, hidden, embed,
                       fuse_b, b_ih, b_hh, ns_b1, ns_b2,
                       rw_b1, rw_W2, rw_b2, dn_b1, dn_W2, dn_b2,
                       ws, out);
}

// Round 15
// 78.821 us; speedup vs baseline: 1.5843x; 1.5843x over previous
//
#include <hip/hip_runtime.h>
#include <hip/hip_bf16.h>
#include <cstddef>
#include <cstdint>

#define BATCH 131072
#define HOFF ((size_t)BATCH * 66)

typedef __attribute__((ext_vector_type(8))) short short8;
typedef __attribute__((ext_vector_type(4))) short short4v;
typedef __attribute__((ext_vector_type(4))) float f32x4;
typedef __attribute__((ext_vector_type(16))) float f32x16;

typedef const __attribute__((address_space(1))) unsigned int* gas_t;
typedef __attribute__((address_space(3))) unsigned int* las_t;

// d_ws (bf16 elems), R13 pair layout (validated):
//  [0,13312): fuse rows 0..127, row-major [128][104] (K padded 80->104)
//  [13312 + (u*3+p)*8704): GRU unit u pair p = [2][32][136]
//     p0: {ir, hr}   p1: {hn, in}   p2: {iz, hz}
//  [117760 + h*8704): head pair h: h0/h1 ns1(q0q1/q2q3), h2 ns2, h3 rw1, h4 dn1
#define WS_G      13312
#define WS_HEAD   117760
#define WS_ELEMS  161280

// smem (shorts): F [0,13312) | 6 pair-slots P0..P5 (8704 each) [13312,65536)
//                | strips 8 x 1280 [65536,75776)  => 151552 B, 1 block/CU
#define PSLOT(s)  (13312 + (s)*8704)
#define STR_BASE  65536

#define MFMA32(a,b,c) __builtin_amdgcn_mfma_f32_32x32x16_bf16((a),(b),(c),0,0,0)

__device__ __forceinline__ short f2bf(float x) {
    __hip_bfloat16 b = __float2bfloat16(x);
    return __builtin_bit_cast(short, b);
}
__device__ __forceinline__ float bf2f(short s) {
    unsigned u = ((unsigned)(unsigned short)s) << 16;
    return __builtin_bit_cast(float, u);
}
__device__ __forceinline__ float fsigmoid(float x) { return __builtin_amdgcn_rcpf(1.0f + __expf(-x)); }
__device__ __forceinline__ float ftanh(float x)    { return 1.0f - 2.0f * __builtin_amdgcn_rcpf(1.0f + __expf(2.0f * x)); }

__device__ __forceinline__ short8 packbf(f32x4 a, f32x4 b) {
    short8 r;
    r[0]=f2bf(a[0]); r[1]=f2bf(a[1]); r[2]=f2bf(a[2]); r[3]=f2bf(a[3]);
    r[4]=f2bf(b[0]); r[5]=f2bf(b[1]); r[6]=f2bf(b[2]); r[7]=f2bf(b[3]);
    return r;
}

// async global->LDS, 512-thread chunking; all NCH tails are multiples of 64 (wave-uniform)
template<int NCH>
__device__ __forceinline__ void stage_lds(const short* __restrict__ src, short* dst, int t) {
    constexpr int NP = (NCH + 511) / 512;
    #pragma unroll
    for (int k = 0; k < NP; ++k) {
        int c = t + 512 * k;
        if ((NCH % 512 == 0) || c < NCH)
            __builtin_amdgcn_global_load_lds((gas_t)(const void*)(src + (size_t)c * 8),
                                             (las_t)(void*)(dst + (size_t)c * 8), 16, 0, 0);
    }
}

// ---------------- prep: f32 weights -> bf16 pair-slots in d_ws (R13 layout, validated) ----------------
extern "C" __global__ void prep_weights(const float* __restrict__ fuse_W,
                                        const float* __restrict__ W_ih, const float* __restrict__ W_hh,
                                        const float* __restrict__ ns_W1, const float* __restrict__ ns_W2,
                                        const float* __restrict__ rw_W1, const float* __restrict__ dn_W1,
                                        short* __restrict__ ws) {
    int i = blockIdx.x * 256 + threadIdx.x;
    if (i >= WS_ELEMS) return;
    float v = 0.f;
    if (i < WS_G) {                          // fuse [128][104]
        int r = i / 104, k = i % 104;
        if (k < 80) v = fuse_W[(size_t)r*80 + k];
    } else if (i < WS_HEAD) {                // GRU pairs
        int rel = i - WS_G;
        int pidx = rel / 8704, e = rel % 8704;
        int q = e / 4352, r = (e % 4352) / 136, k = e % 136;
        if (k < 128) {
            int u = pidx / 3, p = pidx % 3;
            const float* W; int gate;
            if (p == 0)      { W = q ? W_hh : W_ih; gate = 0; }   // {ir, hr}
            else if (p == 1) { W = q ? W_ih : W_hh; gate = 2; }   // {hn, in}
            else             { W = q ? W_hh : W_ih; gate = 1; }   // {iz, hz}
            v = W[(size_t)(gate*128 + u*32 + r)*128 + k];
        }
    } else {                                 // head pairs
        int rel = i - WS_HEAD;
        int h = rel / 8704, e = rel % 8704;
        int q = e / 4352, r = (e % 4352) / 136, k = e % 136;
        if (k < 128) {
            const float* W; int rb;
            if (h == 0)      { W = ns_W1; rb = q*32; }
            else if (h == 1) { W = ns_W1; rb = 64 + q*32; }
            else if (h == 2) { W = ns_W2; rb = q*32; }
            else if (h == 3) { W = rw_W1; rb = q*32; }
            else             { W = dn_W1; rb = q*32; }
            v = W[(size_t)(rb + r)*128 + k];
        }
    }
    ws[i] = f2bf(v);
}

// GRU r-phase from pair slot SB={ir,hr}: strip-transpose h0 slice, rg -> tmp  (R10 internals)
#define GRU_R(SB, U) do {                                                                  \
    *(short8*)&S[ln*40 + hb8]      = ha[2*(U)];                                            \
    *(short8*)&S[ln*40 + 16 + hb8] = ha[2*(U)+1];                                          \
    _Pragma("unroll") for (int p = 0; p < 8; ++p) {                                        \
        const int r0 = 2*p, r1 = 2*p + 1;                                                  \
        unsigned a = (unsigned short)S[((r0&3) + 8*(r0>>2) + hr4)*40 + ln];                \
        unsigned b = (unsigned short)S[((r1&3) + 8*(r1>>2) + hr4)*40 + ln];                \
        h0p[p] = a | (b << 16);                                                            \
    }                                                                                      \
    const int cb = (U)*32 + ln;                                                            \
    const float br = b_ih[cb] + b_hh[cb];                                                  \
    f32x16 acc = zz16;                                                                     \
    _Pragma("unroll") for (int kf = 0; kf < 8; ++kf) {                                     \
        const int ko = kf*16 + hb8;                                                        \
        short8 B0 = *(const short8*)&smem[(SB) + ln*136 + ko];                             \
        acc = MFMA32(xa[kf], B0, acc);                                                     \
        short8 B1 = *(const short8*)&smem[(SB) + 4352 + ln*136 + ko];                      \
        acc = MFMA32(ha[kf], B1, acc);                                                     \
    }                                                                                      \
    _Pragma("unroll") for (int reg = 0; reg < 16; ++reg)                                   \
        tmp[reg] = fsigmoid(acc[reg] + br);                                                \
} while (0)

// GRU n-phase from pair slot SB={hn,in}: tmp = tanh(ain + bin + rg*(ahn + bhn))
#define GRU_N(SB, U) do {                                                                  \
    const int cb = (U)*32 + ln;                                                            \
    const float bin = b_ih[256 + cb], bhn = b_hh[256 + cb];                                \
    f32x16 acc = zz16;                                                                     \
    _Pragma("unroll") for (int kf = 0; kf < 8; ++kf) {                                     \
        short8 B = *(const short8*)&smem[(SB) + ln*136 + kf*16 + hb8];                     \
        acc = MFMA32(ha[kf], B, acc);                                                      \
    }                                                                                      \
    _Pragma("unroll") for (int reg = 0; reg < 16; ++reg)                                   \
        tmp[reg] = tmp[reg] * (acc[reg] + bhn);                                            \
    acc = zz16;                                                                            \
    _Pragma("unroll") for (int kf = 0; kf < 8; ++kf) {                                     \
        short8 B = *(const short8*)&smem[(SB) + 4352 + ln*136 + kf*16 + hb8];              \
        acc = MFMA32(xa[kf], B, acc);                                                      \
    }                                                                                      \
    _Pragma("unroll") for (int reg = 0; reg < 16; ++reg)                                   \
        tmp[reg] = ftanh(acc[reg] + bin + tmp[reg]);                                       \
} while (0)

// GRU z-phase from pair slot SB={iz,hz}: h_new -> strip, capture hfa, coalesced store
#define GRU_Z(SB, U) do {                                                                  \
    const int cb = (U)*32 + ln;                                                            \
    const float bz = b_ih[128 + cb] + b_hh[128 + cb];                                      \
    f32x16 acc = zz16;                                                                     \
    _Pragma("unroll") for (int kf = 0; kf < 8; ++kf) {                                     \
        const int ko = kf*16 + hb8;                                                        \
        short8 B0 = *(const short8*)&smem[(SB) + ln*136 + ko];                             \
        acc = MFMA32(xa[kf], B0, acc);                                                     \
        short8 B1 = *(const short8*)&smem[(SB) + 4352 + ln*136 + ko];                      \
        acc = MFMA32(ha[kf], B1, acc);                                                     \
    }                                                                                      \
    _Pragma("unroll") for (int p = 0; p < 8; ++p) {                                        \
        unsigned hp = h0p[p];                                                              \
        _Pragma("unroll") for (int q = 0; q < 2; ++q) {                                    \
            const int reg = 2*p + q;                                                       \
            float h0v = bf2f((short)(q ? (hp >> 16) : (hp & 0xffffu)));                    \
            float zg = fsigmoid(acc[reg] + bz);                                            \
            S[((reg&3) + 8*(reg>>2) + hr4)*40 + ln] = f2bf((1.f - zg)*tmp[reg] + zg*h0v);  \
        }                                                                                  \
    }                                                                                      \
    hfa[2*(U)]   = *(const short8*)&S[ln*40 + hb8];                                        \
    hfa[2*(U)+1] = *(const short8*)&S[ln*40 + 16 + hb8];                                   \
    store_hnew(U);                                                                         \
} while (0)

// head GEMM: one 32-col group from unit base UB -> strip
#define HEAD32(FRAG, BIASEXPR, UB, RELU) do {                                              \
    f32x16 a = zz16;                                                                       \
    _Pragma("unroll") for (int kf = 0; kf < 8; ++kf) {                                     \
        short8 B = *(const short8*)&smem[(UB) + ln*136 + kf*16 + hb8];                     \
        a = MFMA32((FRAG)[kf], B, a);                                                      \
    }                                                                                      \
    const float bb = (BIASEXPR);                                                           \
    _Pragma("unroll") for (int reg = 0; reg < 16; ++reg) {                                 \
        float v = a[reg] + bb;                                                             \
        if (RELU) v = fmaxf(v, 0.f);                                                       \
        S[((reg&3) + 8*(reg>>2) + hr4)*40 + ln] = f2bf(v);                                 \
    }                                                                                      \
} while (0)

// ---------------- main fused kernel: 512 threads (8 waves x 32 rows), grid 512 ----------------
extern "C" __global__ __launch_bounds__(512, 1)
void gru_mfma(const float* __restrict__ z_t, const int* __restrict__ action,
              const float* __restrict__ hidden, const float* __restrict__ embed,
              const float* __restrict__ fuse_b,
              const float* __restrict__ b_ih, const float* __restrict__ b_hh,
              const float* __restrict__ ns_b1, const float* __restrict__ ns_b2,
              const float* __restrict__ rw_b1, const float* __restrict__ rw_W2, const float* __restrict__ rw_b2,
              const float* __restrict__ dn_b1, const float* __restrict__ dn_W2, const float* __restrict__ dn_b2,
              const short* __restrict__ ws, float* out)
{
    __shared__ __align__(16) short smem[75776];   // 151.5 KB -> 1 block/CU

    const int t    = threadIdx.x;
    const int lane = t & 63;
    const int w    = t >> 6;
    const int ln   = lane & 31;
    const int hb8  = (lane >> 5) * 8;
    const int hr4  = (lane >> 5) * 4;
    const int R    = blockIdx.x * 256 + w * 32;
    short* const S = &smem[STR_BASE + w * 1280];  // per-wave strip [32][40]

    const f32x16 zz16 = {0,0,0,0,0,0,0,0,0,0,0,0,0,0,0,0};

    auto store_hnew = [&](int j2) {
        #pragma unroll
        for (int v = 0; v < 4; ++v) {
            int idx = v*64 + lane;
            int r = idx >> 3, c = (idx & 7) * 4;
            short4v s = *(const short4v*)&S[r*40 + c];
            f32x4 f = { bf2f(s[0]), bf2f(s[1]), bf2f(s[2]), bf2f(s[3]) };
            *(f32x4*)&out[HOFF + (size_t)(R + r)*128 + j2*32 + c] = f;
        }
    };
    auto store_z = [&](int q) {
        #pragma unroll
        for (int v = 0; v < 4; ++v) {
            int idx = v*64 + lane;
            int r = idx >> 3, c = (idx & 7) * 4;
            short4v s = *(const short4v*)&S[r*40 + c];
            f32x4 f = { bf2f(s[0]), bf2f(s[1]), bf2f(s[2]), bf2f(s[3]) };
            *(f32x4*)&out[(size_t)(R + r)*64 + q*32 + c] = f;
        }
    };
    auto hpartial = [&](const float* W2, float acc) -> float {
        int rr = lane & 31;
        #pragma unroll
        for (int kk = 0; kk < 32; kk += 8) {
            short8 s = *(const short8*)&S[rr*40 + kk];
            f32x4 w0 = *(const f32x4*)&W2[kk];
            f32x4 w1 = *(const f32x4*)&W2[kk+4];
            acc += bf2f(s[0])*w0[0] + bf2f(s[1])*w0[1] + bf2f(s[2])*w0[2] + bf2f(s[3])*w0[3]
                 + bf2f(s[4])*w1[0] + bf2f(s[5])*w1[1] + bf2f(s[6])*w1[2] + bf2f(s[7])*w1[3];
        }
        return acc;
    };

    // ---- initial stage (only uncovered one): fuse -> F, units 0,1 (6 pairs) -> P0..P5 ----
    stage_lds<1664>(ws, &smem[0], t);
    stage_lds<6528>(ws + WS_G, &smem[PSLOT(0)], t);

    // ---- A-fragments direct from global (row = R + ln), f32 -> bf16 ----
    short8 fa[5];
    short8 ha[8];
    {
        const int row = R + ln;
        #pragma unroll
        for (int kf = 0; kf < 4; ++kf) {
            f32x4 p0 = *(const f32x4*)&z_t[(size_t)row*64 + kf*16 + hb8];
            f32x4 p1 = *(const f32x4*)&z_t[(size_t)row*64 + kf*16 + hb8 + 4];
            fa[kf] = packbf(p0, p1);
        }
        int a = action[row];
        f32x4 e0 = *(const f32x4*)&embed[a*16 + hb8];
        f32x4 e1 = *(const f32x4*)&embed[a*16 + hb8 + 4];
        fa[4] = packbf(e0, e1);
        #pragma unroll
        for (int kf = 0; kf < 8; ++kf) {
            f32x4 p0 = *(const f32x4*)&hidden[(size_t)row*128 + kf*16 + hb8];
            f32x4 p1 = *(const f32x4*)&hidden[(size_t)row*128 + kf*16 + hb8 + 4];
            ha[kf] = packbf(p0, p1);
        }
    }

    short8 xa[8], hfa[8];
    f32x16 tmp;
    unsigned h0p[8];

    __syncthreads();                                   // B1: F + units 0,1 resident

    // ---- fuse: 4 col-tiles from F; xa frags via strip ----
    #pragma unroll
    for (int n = 0; n < 4; ++n) {
        f32x16 a = zz16;
        #pragma unroll
        for (int kf = 0; kf < 5; ++kf) {
            short8 B = *(const short8*)&smem[(n*32 + ln)*104 + kf*16 + hb8];
            a = MFMA32(fa[kf], B, a);
        }
        float fb = fuse_b[n*32 + ln];
        #pragma unroll
        for (int reg = 0; reg < 16; ++reg)
            S[((reg&3) + 8*(reg>>2) + hr4)*40 + ln] = f2bf(fmaxf(a[reg] + fb, 0.f));
        xa[2*n]   = *(const short8*)&S[ln*40 + hb8];
        xa[2*n+1] = *(const short8*)&S[ln*40 + 16 + hb8];
    }

    // ---- GRU unit 0 from P0,P1,P2 ----
    GRU_R(PSLOT(0), 0);
    GRU_N(PSLOT(1), 0);
    GRU_Z(PSLOT(2), 0);

    __syncthreads();                                   // B2: all waves done with P0-P2
    stage_lds<3264>(ws + WS_G + 6*8704, &smem[PSLOT(0)], t);   // unit 2 (pidx 6-8) -> P0-P2

    // ---- GRU unit 1 from P3,P4,P5 (covers the stage above) ----
    GRU_R(PSLOT(3), 1);
    GRU_N(PSLOT(4), 1);
    GRU_Z(PSLOT(5), 1);

    __syncthreads();                                   // B3: unit 2 resident; done with P3-P5
    stage_lds<3264>(ws + WS_G + 9*8704, &smem[PSLOT(3)], t);   // unit 3 (pidx 9-11) -> P3-P5

    // ---- GRU unit 2 from P0,P1,P2 ----
    GRU_R(PSLOT(0), 2);
    GRU_N(PSLOT(1), 2);
    GRU_Z(PSLOT(2), 2);

    __syncthreads();                                   // B4: unit 3 resident; done with P0-P2
    stage_lds<3264>(ws + WS_HEAD, &smem[PSLOT(0)], t); // heads h0,h1,h2 -> P0-P2

    // ---- GRU unit 3 from P3,P4,P5 ----
    GRU_R(PSLOT(3), 3);
    GRU_N(PSLOT(4), 3);
    GRU_Z(PSLOT(5), 3);

    __syncthreads();                                   // B5: h0,h1,h2 resident; done with P3-P5
    stage_lds<2176>(ws + WS_HEAD + 3*8704, &smem[PSLOT(3)], t);   // h3,h4 -> P3,P4

    // ---- heads part 1: ns1 (P0,P1), ns2 (P2) ----
    short8 ta[8];
    HEAD32(hfa, ns_b1[ln],      PSLOT(0),        true);
    ta[0] = *(const short8*)&S[ln*40 + hb8];
    ta[1] = *(const short8*)&S[ln*40 + 16 + hb8];
    HEAD32(hfa, ns_b1[32 + ln], PSLOT(0) + 4352, true);
    ta[2] = *(const short8*)&S[ln*40 + hb8];
    ta[3] = *(const short8*)&S[ln*40 + 16 + hb8];
    HEAD32(hfa, ns_b1[64 + ln], PSLOT(1),        true);
    ta[4] = *(const short8*)&S[ln*40 + hb8];
    ta[5] = *(const short8*)&S[ln*40 + 16 + hb8];
    HEAD32(hfa, ns_b1[96 + ln], PSLOT(1) + 4352, true);
    ta[6] = *(const short8*)&S[ln*40 + hb8];
    ta[7] = *(const short8*)&S[ln*40 + 16 + hb8];

    HEAD32(ta, ns_b2[ln],      PSLOT(2),        false); store_z(0);
    HEAD32(ta, ns_b2[32 + ln], PSLOT(2) + 4352, false); store_z(1);

    __syncthreads();                                   // B6: h3,h4 resident

    // ---- heads part 2: rw1 (P3) + reward, dn1 (P4) + done ----
    float racc = rw_b2[0];
    HEAD32(hfa, rw_b1[ln],      PSLOT(3),        true); racc = hpartial(rw_W2, racc);
    HEAD32(hfa, rw_b1[32 + ln], PSLOT(3) + 4352, true); racc = hpartial(rw_W2 + 32, racc);
    if (lane < 32) out[(size_t)BATCH*64 + R + ln] = racc;

    float dacc = dn_b2[0];
    HEAD32(hfa, dn_b1[ln],      PSLOT(4),        true); dacc = hpartial(dn_W2, dacc);
    HEAD32(hfa, dn_b1[32 + ln], PSLOT(4) + 4352, true); dacc = hpartial(dn_W2 + 32, dacc);
    if (lane < 32) out[(size_t)BATCH*65 + R + ln] = dacc;
}

extern "C" void kernel_launch(void* const* d_in, const int* in_sizes, int n_in,
                              void* d_out, int out_size, void* d_ws, size_t ws_size,
                              hipStream_t stream) {
    const float* z_t    = (const float*)d_in[0];
    const int*   action = (const int*)  d_in[1];
    const float* hidden = (const float*)d_in[2];
    const float* embed  = (const float*)d_in[3];
    const float* fuse_W = (const float*)d_in[4];
    const float* fuse_b = (const float*)d_in[5];
    const float* W_ih   = (const float*)d_in[6];
    const float* W_hh   = (const float*)d_in[7];
    const float* b_ih   = (const float*)d_in[8];
    const float* b_hh   = (const float*)d_in[9];
    const float* ns_W1  = (const float*)d_in[10];
    const float* ns_b1  = (const float*)d_in[11];
    const float* ns_W2  = (const float*)d_in[12];
    const float* ns_b2  = (const float*)d_in[13];
    const float* rw_W1  = (const float*)d_in[14];
    const float* rw_b1  = (const float*)d_in[15];
    const float* rw_W2  = (const float*)d_in[16];
    const float* rw_b2  = (const float*)d_in[17];
    const float* dn_W1  = (const float*)d_in[18];
    const float* dn_b1  = (const float*)d_in[19];
    const float* dn_W2  = (const float*)d_in[20];
    const float* dn_b2  = (const float*)d_in[21];
    float* out = (float*)d_out;
    short* ws  = (short*)d_ws;

    hipLaunchKernelGGL(prep_weights, dim3((WS_ELEMS + 255) / 256), dim3(256), 0, stream,
                       fuse_W, W_ih, W_hh, ns_W1, ns_W2, rw_W1, dn_W1, ws);

    hipLaunchKernelGGL(gru_mfma, dim3(BATCH / 256), dim3(512), 0, stream,
                       z_t, action, hidden, embed,
                       fuse_b, b_ih, b_hh, ns_b1, ns_b2,
                       rw_b1, rw_W2, rw_b2, dn_b1, dn_W2, dn_b2,
                       ws, out);
}